// Round 16
// baseline (55.733 us; speedup 1.0000x reference)
//
#include <hip/hip_runtime.h>
#include <math.h>

#define C_DIM 128
#define H_DIM 128
#define W_DIM 128
#define HW (H_DIM * W_DIM)
#define EPS_N 1e-12f
#define RST 8                  // rows per stripe
#define NSTR (H_DIM / RST)     // 16 stripes per image
#define SLC 16                 // channels per slice
#define NSL (C_DIM / SLC)      // 8 slices
#define CHK 4                  // channels per LDS chunk
#define NCHK (SLC / CHK)       // 4 chunks per slice
#define LW 136                 // staged row: 4 zero-pad + 128 data + 4 zero-pad
#define NPL 11                 // partial planes: 9 dots + fe2 + norm2
#define PS (NPL * W_DIM)
#define LD2(p) (*(const float2*)(p))
#define LD4(p) (*(const float4*)(p))

// Traffic-minimizing stripe design: fu rows staged once per stripe (1.25x vs
// the 3x u/m/d re-reads of row-block designs). All accumulation thread-local
// (thread owns 2 adjacent px of one row) -> no shuffles, no reduces.
// OOB rows/cols staged as exact 0 -> their dots contribute 0 (matches the
// zero-padded unfold); softmax ok[]-masking is R12-measured verbatim.

// decode helpers: wb = ((bz*NSTR)+st)*NSL + sl, with XCD-chunked swizzle so all
// 8 slices of a stripe (sharing fe rows + partial rows) land on one XCD.

// ---------------- k2: per-(stripe,slice) partial dots + fe2 + norm2 ----------------
__global__ __launch_bounds__(512) void k2s(const float* __restrict__ fe,
                                           const float* __restrict__ fu,
                                           float* __restrict__ pgA)
{
    __shared__ float fuS[CHK][RST + 2][LW];   // 21.8 KB

    const int tid = threadIdx.x;
    const int bid = blockIdx.x;
    const int cpx = gridDim.x >> 3;
    const int wb  = (bid & 7) * cpx + (bid >> 3);
    const int sl  = wb & (NSL - 1);
    const int st  = (wb >> 3) & (NSTR - 1);
    const int bz  = wb >> 7;

    const int r0 = st * RST;
    const int c0 = sl * SLC;
    const int pr   = tid >> 6;          // wave = one pixel row
    const int col0 = (tid & 63) * 2;    // lane owns px col0, col0+1
    const int row  = r0 + pr;

    float2 dk[9];
#pragma unroll
    for (int k = 0; k < 9; ++k) dk[k] = make_float2(0.f, 0.f);
    float2 fe2 = make_float2(0.f, 0.f);
    float2 n2  = make_float2(0.f, 0.f);

    // zero the halo pads once (cols 0..3 and 132..135 of each staged row)
    if (tid < CHK * (RST + 2) * 2) {
        const int q = tid >> 1, side = tid & 1;
        *(float4*)&fuS[q / (RST + 2)][q % (RST + 2)][side ? (LW - 4) : 0] =
            make_float4(0.f, 0.f, 0.f, 0.f);
    }
    __syncthreads();

    for (int ck = 0; ck < NCHK; ++ck) {
        // stage: 4 ch x 10 rows x 128 cols (zeros for OOB image rows)
        for (int t = tid; t < CHK * (RST + 2) * 32; t += 512) {
            const int q = t >> 5, c4 = (t & 31) * 4;
            const int ch = q / (RST + 2), sr = q % (RST + 2);
            const int grow = r0 - 1 + sr;
            float4 v = make_float4(0.f, 0.f, 0.f, 0.f);
            if (grow >= 0 && grow < H_DIM)
                v = LD4(fu + ((size_t)bz * C_DIM + c0 + ck * CHK + ch) * HW
                        + grow * W_DIM + c4);
            *(float4*)&fuS[ch][sr][4 + c4] = v;
        }
        __syncthreads();

#pragma unroll
        for (int ch = 0; ch < CHK; ++ch) {
            const float2 f = LD2(fe + ((size_t)bz * C_DIM + c0 + ck * CHK + ch) * HW
                                 + row * W_DIM + col0);
            fe2.x += f.x * f.x; fe2.y += f.y * f.y;
#pragma unroll
            for (int dr = 0; dr < 3; ++dr) {
                const float* rp = &fuS[ch][pr + dr][4 + col0];
                const float vm1 = rp[-1], v0 = rp[0], v1 = rp[1], v2 = rp[2];
                dk[3*dr+0].x += f.x * vm1; dk[3*dr+1].x += f.x * v0; dk[3*dr+2].x += f.x * v1;
                dk[3*dr+0].y += f.y * v0;  dk[3*dr+1].y += f.y * v1; dk[3*dr+2].y += f.y * v2;
                if (dr == 1) { n2.x += v0 * v0; n2.y += v1 * v1; }   // own-row norm2
            }
        }
        __syncthreads();
    }

    // write partials: [RG][slice][plane][col]
    const int RG = bz * H_DIM + row;
    float* dst = pgA + ((size_t)RG * NSL + sl) * PS;
#pragma unroll
    for (int k = 0; k < 9; ++k) *(float2*)&dst[k * W_DIM + col0] = dk[k];
    *(float2*)&dst[9 * W_DIM + col0]  = fe2;
    *(float2*)&dst[10 * W_DIM + col0] = n2;
}

// ---------------- k2.5: reduce partials across slices ----------------
// pgB[RG][10][128] = sum of dot/fe2 planes; pgN[RG][128] = 1/max(sqrt(norm2),eps)
__global__ __launch_bounds__(256) void k25(const float* __restrict__ pgA,
                                           float* __restrict__ pgB,
                                           float* __restrict__ pgN)
{
    const int tid = threadIdx.x;
    const int RG0 = blockIdx.x * 2;
    for (int t = tid; t < 2 * NPL * 32; t += 256) {
        const int r = t / (NPL * 32);
        const int rem = t - r * (NPL * 32);
        const int pl = rem >> 5, c4 = (rem & 31) * 4;
        const int RG = RG0 + r;
        const float* src = pgA + (size_t)RG * NSL * PS + pl * W_DIM + c4;
        float4 s = make_float4(0.f, 0.f, 0.f, 0.f);
#pragma unroll
        for (int s8 = 0; s8 < NSL; ++s8) {
            const float4 v = LD4(src + (size_t)s8 * PS);
            s.x += v.x; s.y += v.y; s.z += v.z; s.w += v.w;
        }
        if (pl < 10) {
            *(float4*)&pgB[((size_t)RG * 10 + pl) * W_DIM + c4] = s;
        } else {
            float4 rr;
            rr.x = 1.f / fmaxf(sqrtf(s.x), EPS_N);
            rr.y = 1.f / fmaxf(sqrtf(s.y), EPS_N);
            rr.z = 1.f / fmaxf(sqrtf(s.z), EPS_N);
            rr.w = 1.f / fmaxf(sqrtf(s.w), EPS_N);
            *(float4*)&pgN[(size_t)RG * W_DIM + c4] = rr;
        }
    }
}

// ---------------- k3: per-thread softmax + staged aggregation + residual ----------------
__global__ __launch_bounds__(512) void k3s(const float* __restrict__ fe,
                                           const float* __restrict__ fu,
                                           const float* __restrict__ pgB,
                                           const float* __restrict__ pgN,
                                           float* __restrict__ out)
{
    __shared__ float fuS[CHK][RST + 2][LW];

    const int tid = threadIdx.x;
    const int bid = blockIdx.x;
    const int cpx = gridDim.x >> 3;
    const int wb  = (bid & 7) * cpx + (bid >> 3);
    const int sl  = wb & (NSL - 1);
    const int st  = (wb >> 3) & (NSTR - 1);
    const int bz  = wb >> 7;

    const int r0 = st * RST;
    const int c0 = sl * SLC;
    const int pr   = tid >> 6;
    const int col0 = (tid & 63) * 2;
    const int row  = r0 + pr;
    const int RG = bz * H_DIM + row;

    // softmax weights for this thread's 2 pixels (R12-measured formula)
    float2 w2[9];
    {
        const float* db = pgB + (size_t)RG * 10 * W_DIM;
        const float2 f2 = LD2(&db[9 * W_DIM + col0]);
        const float rfe_x = 1.f / fmaxf(sqrtf(f2.x), EPS_N);
        const float rfe_y = 1.f / fmaxf(sqrtf(f2.y), EPS_N);
        float csx[9], csy[9];
        float mxx = -1e30f, mxy = -1e30f;
#pragma unroll
        for (int k = 0; k < 9; ++k) {
            const int di = k / 3, dj = k % 3;
            const int nr = row + di - 1;
            const int nrc = min(max(nr, 0), H_DIM - 1);
            const float2 dv = LD2(&db[k * W_DIM + col0]);
            const float* np = pgN + (size_t)(bz * H_DIM + nrc) * W_DIM;
            // px0 = col0
            {
                const int nc = col0 + dj - 1;
                const bool ok = (nr >= 0 && nr < H_DIM && nc >= 0 && nc < W_DIM);
                const int ncc = min(max(nc, 0), W_DIM - 1);
                const float cv = ok ? dv.x * rfe_x * np[ncc] : 0.f;
                csx[k] = cv; mxx = fmaxf(mxx, cv);
            }
            // px1 = col0+1
            {
                const int nc = col0 + dj;
                const bool ok = (nr >= 0 && nr < H_DIM && nc >= 0 && nc < W_DIM);
                const int ncc = min(max(nc, 0), W_DIM - 1);
                const float cv = ok ? dv.y * rfe_y * np[ncc] : 0.f;
                csy[k] = cv; mxy = fmaxf(mxy, cv);
            }
        }
        float sx = 0.f, sy = 0.f;
#pragma unroll
        for (int k = 0; k < 9; ++k) {
            csx[k] = __expf(csx[k] - mxx); sx += csx[k];
            csy[k] = __expf(csy[k] - mxy); sy += csy[k];
        }
        const float isx = 1.f / sx, isy = 1.f / sy;
#pragma unroll
        for (int k = 0; k < 9; ++k) { w2[k].x = csx[k] * isx; w2[k].y = csy[k] * isy; }
    }

    // zero halo pads
    if (tid < CHK * (RST + 2) * 2) {
        const int q = tid >> 1, side = tid & 1;
        *(float4*)&fuS[q / (RST + 2)][q % (RST + 2)][side ? (LW - 4) : 0] =
            make_float4(0.f, 0.f, 0.f, 0.f);
    }
    __syncthreads();

    for (int ck = 0; ck < NCHK; ++ck) {
        for (int t = tid; t < CHK * (RST + 2) * 32; t += 512) {
            const int q = t >> 5, c4 = (t & 31) * 4;
            const int ch = q / (RST + 2), sr = q % (RST + 2);
            const int grow = r0 - 1 + sr;
            float4 v = make_float4(0.f, 0.f, 0.f, 0.f);
            if (grow >= 0 && grow < H_DIM)
                v = LD4(fu + ((size_t)bz * C_DIM + c0 + ck * CHK + ch) * HW
                        + grow * W_DIM + c4);
            *(float4*)&fuS[ch][sr][4 + c4] = v;
        }
        __syncthreads();

#pragma unroll
        for (int ch = 0; ch < CHK; ++ch) {
            const size_t chbase = ((size_t)bz * C_DIM + c0 + ck * CHK + ch) * HW
                                  + row * W_DIM + col0;
            const float2 f = LD2(fe + chbase);
            float2 acc = f;   // residual
#pragma unroll
            for (int dr = 0; dr < 3; ++dr) {
                const float* rp = &fuS[ch][pr + dr][4 + col0];
                const float vm1 = rp[-1], v0 = rp[0], v1 = rp[1], v2 = rp[2];
                acc.x += w2[3*dr+0].x * vm1 + w2[3*dr+1].x * v0 + w2[3*dr+2].x * v1;
                acc.y += w2[3*dr+0].y * v0  + w2[3*dr+1].y * v1 + w2[3*dr+2].y * v2;
            }
            *(float2*)(out + chbase) = acc;
        }
        __syncthreads();
    }
}

extern "C" void kernel_launch(void* const* d_in, const int* in_sizes, int n_in,
                              void* d_out, int out_size, void* d_ws, size_t ws_size,
                              hipStream_t stream) {
    const float* fe = (const float*)d_in[0];   // fe_lv
    const float* fu = (const float*)d_in[1];   // fused_features
    float* out = (float*)d_out;
    const int B = in_sizes[0] / (C_DIM * HW);
    const int RGtot = B * H_DIM;

    float* pgA = (float*)d_ws;                       // RGtot*8*1408 (23 MB @ B=4)
    float* pgB = pgA + (size_t)RGtot * NSL * PS;     // RGtot*10*128 (2.6 MB)
    float* pgN = pgB + (size_t)RGtot * 10 * W_DIM;   // RGtot*128    (0.26 MB)

    dim3 g2(B * NSTR * NSL);                  // 512 blocks @ B=4 (%8==0)
    k2s<<<g2, 512, 0, stream>>>(fe, fu, pgA);

    dim3 g25(RGtot / 2);                      // 256 blocks
    k25<<<g25, 256, 0, stream>>>(pgA, pgB, pgN);

    k3s<<<g2, 512, 0, stream>>>(fe, fu, pgB, pgN, out);
}